// Round 9
// baseline (64.389 us; speedup 1.0000x reference)
//
#include <hip/hip_runtime.h>
#include <hip/hip_fp16.h>

#define N 224        // image size
#define M 32         // CUT (number of sine modes)
#define NPIX (N * N) // 50176
#define NPLANE 384   // 128 * 3
#define PLT 128      // planes per group
#define NPGRP 3      // 384 / 128
#define TPX 256      // transpose pixel tile
#define NTTILE (NPIX / TPX)   // 196
#define RPX 128      // remap pixel tile
#define NCHUNK (NPIX / RPX)   // 392
#define NXCD 8
#define CPX (NCHUNK / NXCD)   // 49
#define PI_F 3.14159265358979323846f

typedef float vfloat4 __attribute__((ext_vector_type(4)));

// ---------------- Stage 1: displacement field -> bilinear table ------------
// tab[pix] = (base = by*N+bx, fx, fy, 0), canonical form (identical to the
// reference's floor/ceil form in all cases incl. integer and clamped coords).
__global__ __launch_bounds__(256) void field_kernel(
    const float* __restrict__ Fx, const float* __restrict__ Fy,
    int4* __restrict__ tab)
{
    __shared__ float cx[M][M];
    __shared__ float cy[M][M];
    __shared__ float sy[M];

    const int t = threadIdx.x;
    const int y = blockIdx.x;

    for (int idx = t; idx < M * M; idx += 256) {
        const int i = idx / M, j = idx % M;
        const float fi = (float)(i + 1), fj = (float)(j + 1);
        const float r = sqrtf(fi * fi + fj * fj);
        const float e = (r < (float)M + 0.5f) ? (1.0f / r) : 0.0f;
        cx[i][j] = Fx[idx] * e;
        cy[i][j] = Fy[idx] * e;
    }
    if (t < M) {
        const float ys = (float)y / (float)(N - 1);
        sy[t] = sinf(PI_F * ys * (float)(t + 1));
    }
    __syncthreads();

    if (t >= N) return;
    const int x = t;

    float sx[M];
    const float xsv = (float)x / (float)(N - 1);
#pragma unroll
    for (int i = 0; i < M; ++i)
        sx[i] = sinf(PI_F * xsv * (float)(i + 1));

    float u = 0.0f, v = 0.0f;
#pragma unroll 1
    for (int j = 0; j < M; ++j) {
        float tx = 0.0f, ty = 0.0f;
#pragma unroll
        for (int i = 0; i < M; ++i) {
            tx = fmaf(cx[i][j], sx[i], tx);
            ty = fmaf(cy[i][j], sx[i], ty);
        }
        const float syj = sy[j];
        u = fmaf(syj, tx, u);
        v = fmaf(syj, ty, v);
    }

    const float dxv = 22.4f * u;   // sqrt(T)*n = 0.1*224
    const float dyv = 22.4f * v;
    const float xn = fminf(fmaxf((float)x + dxv, 0.0f), (float)(N - 1));
    const float yn = fminf(fmaxf((float)y + dyv, 0.0f), (float)(N - 1));
    const int bx = min((int)floorf(xn), N - 2);
    const int by = min((int)floorf(yn), N - 2);
    const float fx = xn - (float)bx;
    const float fy = yn - (float)by;

    tab[y * N + x] = make_int4(by * N + bx,
                               __float_as_int(fx), __float_as_int(fy), 0);
}

// --- Stage 2: transpose x[384][50176] f32 -> xt[3][50176][128] fp16 --------
// Tile: 128 planes x 256 pixels. Load: 64 lanes x float4 = 1024 B contiguous
// per wave-inst. LDS [plane][256+10] halves (stride 266: store-phase half2
// reads land on 8+ banks, ~2-way). Store: per lane, half2-pair reads give 4
// planes of TWO adjacent pixels -> two uint2 stores (2x256 B segs/inst).
__global__ __launch_bounds__(256) void transpose_kernel(
    const float* __restrict__ x, __half* __restrict__ xt)
{
    __shared__ __half t[PLT][TPX + 10];   // stride 266 halves

    const int tid = threadIdx.x;
    const int w = tid >> 6, l = tid & 63;
    const int pg   = blockIdx.x / NTTILE;
    const int tile = blockIdx.x % NTTILE;
    const int pix0 = tile * TPX;
    const int plane0 = pg * PLT;

#pragma unroll
    for (int i = 0; i < 32; ++i) {
        const int p = w * 32 + i;         // local plane 0..127
        const vfloat4 v = *(const vfloat4*)(
            x + (size_t)(plane0 + p) * NPIX + pix0 + 4 * l);
        *(__half2*)&t[p][4 * l]     = __floats2half2_rn(v.x, v.y);
        *(__half2*)&t[p][4 * l + 2] = __floats2half2_rn(v.z, v.w);
    }
    __syncthreads();

    __half* xo = xt + ((size_t)pg * NPIX + pix0) * PLT;
    const int c = l & 31, hg = l >> 5;
#pragma unroll
    for (int s = 0; s < 16; ++s) {
        const int pair = w * 32 + hg * 16 + s;   // 0..127
        const int P = 2 * pair;
        const __half2 a0 = *(const __half2*)&t[4 * c + 0][P];
        const __half2 a1 = *(const __half2*)&t[4 * c + 1][P];
        const __half2 a2 = *(const __half2*)&t[4 * c + 2][P];
        const __half2 a3 = *(const __half2*)&t[4 * c + 3][P];
        union { uint2 u; __half2 hh[2]; } p0, p1;
        p0.hh[0] = __halves2half2(__low2half(a0),  __low2half(a1));
        p0.hh[1] = __halves2half2(__low2half(a2),  __low2half(a3));
        p1.hh[0] = __halves2half2(__high2half(a0), __high2half(a1));
        p1.hh[1] = __halves2half2(__high2half(a2), __high2half(a3));
        *(uint2*)&xo[(size_t)P * PLT + 4 * c]       = p0.u;
        *(uint2*)&xo[(size_t)(P + 1) * PLT + 4 * c] = p1.u;
    }
}

// --- Stage 3: remap, planes-in-lanes (all VMEM coalesced) ------------------
// Block = 128 pixels x 128 planes. Gather: per pixel, 4 coalesced half2
// loads (lane = plane-pair). Result written to LDS [plane][px] with XOR
// swizzle col ^= ((row>>3)&7)<<2 (breaks the 16-way stride pattern; float4
// groups preserved). Store: float4/lane nontemporal, 2x512 B segs/inst.
// Grid XCD-clustered: xcd owns pixel chunks [xcd*49,(xcd+1)*49) per pgrp.
__global__ __launch_bounds__(256) void remap_kernel(
    const __half* __restrict__ xt, const int4* __restrict__ tab,
    float* __restrict__ out)
{
    __shared__ float tileT[PLT][RPX + 4];  // stride 132 words (16B-aligned rows)
    __shared__ int4 ltab[RPX];

    const int tid = threadIdx.x;
    const int w = tid >> 6, l = tid & 63;

    const int bid   = blockIdx.x;
    const int xcd   = bid & 7;
    const int local = bid >> 3;          // 0..146
    const int pg    = local / CPX;       // 0..2
    const int chunk = xcd * CPX + (local % CPX);
    const int pix0  = chunk * RPX;

    if (tid < RPX) ltab[tid] = tab[pix0 + tid];
    __syncthreads();

    const __half2* base = (const __half2*)(xt + (size_t)pg * NPIX * PLT);
    const int r0 = 2 * l, r1 = 2 * l + 1;
    const int sw0 = ((r0 >> 3) & 7) << 2;   // XOR swizzle for row 2l
    const int sw1 = ((r1 >> 3) & 7) << 2;   // XOR swizzle for row 2l+1

#pragma unroll 8
    for (int i = 0; i < 32; ++i) {
        const int pl = w * 32 + i;       // pixel-local index 0..127
        const int4 tb = ltab[pl];
        const float fx = __int_as_float(tb.y);
        const float fy = __int_as_float(tb.z);
        const float omx = 1.0f - fx, omy = 1.0f - fy;
        const float w00 = omy * omx, w01 = omy * fx;
        const float w10 = fy * omx,  w11 = fy * fx;

        const size_t b0 = (size_t)tb.x * (PLT / 2);   // half2 units
        const float2 c00 = __half22float2(base[b0 + l]);
        const float2 c01 = __half22float2(base[b0 + PLT / 2 + l]);
        const float2 c10 = __half22float2(base[b0 + (size_t)N * (PLT / 2) + l]);
        const float2 c11 = __half22float2(base[b0 + (size_t)N * (PLT / 2) + PLT / 2 + l]);

        const float ox = w00 * c00.x + w01 * c01.x + w10 * c10.x + w11 * c11.x;
        const float oy = w00 * c00.y + w01 * c01.y + w10 * c10.y + w11 * c11.y;
        tileT[r0][pl ^ sw0] = ox;        // plane 2l   of pixel pl
        tileT[r1][pl ^ sw1] = oy;        // plane 2l+1 of pixel pl
    }
    __syncthreads();

    const int c = l & 31, hg = l >> 5;
    float* ob = out + (size_t)pg * PLT * NPIX + pix0;
#pragma unroll
    for (int s = 0; s < 16; ++s) {
        const int j = w * 32 + hg * 16 + s;           // plane 0..127
        const int swj = ((j >> 3) & 7) << 2;
        const vfloat4 o4 = *(const vfloat4*)&tileT[j][(4 * c) ^ swj];
        __builtin_nontemporal_store(o4, (vfloat4*)&ob[(size_t)j * NPIX + 4 * c]);
    }
}

extern "C" void kernel_launch(void* const* d_in, const int* in_sizes, int n_in,
                              void* d_out, int out_size, void* d_ws, size_t ws_size,
                              hipStream_t stream) {
    const float* x  = (const float*)d_in[0];   // [128,3,224,224]
    const float* Fx = (const float*)d_in[1];   // [32,32]
    const float* Fy = (const float*)d_in[2];   // [32,32]
    float* out = (float*)d_out;

    int4* tab = (int4*)d_ws;                               // 802,816 B
    const size_t tab_bytes = (size_t)NPIX * sizeof(int4);
    __half* xt = (__half*)((char*)d_ws + tab_bytes);       // 38.5 MB

    field_kernel<<<N, 256, 0, stream>>>(Fx, Fy, tab);
    transpose_kernel<<<NPGRP * NTTILE, 256, 0, stream>>>(x, xt);
    remap_kernel<<<NCHUNK * NPGRP, 256, 0, stream>>>(xt, tab, out);
}